// Round 7
// baseline (343.729 us; speedup 1.0000x reference)
//
#include <hip/hip_runtime.h>
#include <math.h>

// Match numpy (no FMA contraction) — mask boundary is bit-sensitive.
#pragma clang fp contract(off)

namespace {

constexpr int B = 12, H = 192, W = 640;
constexpr int HW  = H * W;        // 122880
constexpr int BHW = B * HW;       // 1474560
constexpr float EPS = 1e-7f;

constexpr int TR    = 12;         // target-tile rows per block
constexpr int TILES = H / TR;     // 16 tiles/batch
constexpr int TRW   = TR * W;     // 7680 targets per tile
constexpr int SC    = 2;          // source chunks per tile
constexpr int HWC   = HW / SC;    // 61440 sources per chunk
constexpr int TPB   = 512;
constexpr int NBLK  = B * TILES * SC;  // 384 blocks; launch_bounds(512,4)
                                       // guarantees >=2 blocks/CU -> 512
                                       // slots >= 384: all co-resident.
constexpr int PPB   = BHW / NBLK;      // 3840 pixels/targets per block

// ws: bar u32[8] @ +0 | redA[NBLK*4] @ +4096 | redB[NBLK*2] @ +12288 |
//     partial[NBLK*TRW] u32 @ +16384   (~11.8 MB, R4-proven size)
// check[] scratch lives in out[0..BHW) between phase B and C.

__device__ __forceinline__ void gridBarrier(unsigned int* cnt, unsigned int* flag) {
    __syncthreads();
    if (threadIdx.x == 0) {
        __threadfence();                       // release: agent-visible stores
        unsigned prev = atomicAdd(cnt, 1u);    // device-scope RMW
        if (prev == (unsigned)(NBLK - 1)) {
            __hip_atomic_store(flag, 1u, __ATOMIC_RELEASE, __HIP_MEMORY_SCOPE_AGENT);
        } else {
            while (__hip_atomic_load(flag, __ATOMIC_ACQUIRE,
                                     __HIP_MEMORY_SCOPE_AGENT) == 0u)
                __builtin_amdgcn_s_sleep(1);
        }
        __threadfence();                       // acquire: drop stale lines
    }
    __syncthreads();
}

// P = (K @ pose)[:3,:] — hoisted per block; per-element arithmetic identical
// to the reference einsum (left-assoc, contract off).
__device__ __forceinline__ void computeP(const float* __restrict__ Kb,
                                         const float* __restrict__ Po, float* P) {
#pragma unroll
    for (int i = 0; i < 3; ++i)
#pragma unroll
        for (int j = 0; j < 4; ++j) {
            float s = Kb[i*4+0] * Po[0*4+j];
            s = s + Kb[i*4+1] * Po[1*4+j];
            s = s + Kb[i*4+2] * Po[2*4+j];
            s = s + Kb[i*4+3] * Po[3*4+j];
            P[i*4+j] = s;
        }
}

__device__ __forceinline__ void static_flow_P(
    const float* __restrict__ iK, const float* __restrict__ P,
    int x, int y, float d, float& sx, float& sy)
{
    float fx = (float)x, fy = (float)y;
    float cam0 = iK[0]*fx + iK[1]*fy + iK[2];
    float cam1 = iK[4]*fx + iK[5]*fy + iK[6];
    float cam2 = iK[8]*fx + iK[9]*fy + iK[10];
    cam0 = d * cam0; cam1 = d * cam1; cam2 = d * cam2;
    float cp0 = P[0]*cam0 + P[1]*cam1 + P[2]*cam2  + P[3];
    float cp1 = P[4]*cam0 + P[5]*cam1 + P[6]*cam2  + P[7];
    float cp2 = P[8]*cam0 + P[9]*cam1 + P[10]*cam2 + P[11];
    float pz = cp2 + EPS;
    sx = cp0 / pz - fx;
    sy = cp1 / pz - fy;
}

__device__ __forceinline__ float norm01(float v, float mn, float mx) {
    return (2.0f * (v - mn)) / (mx - mn) - 1.0f;
}

// Block-wide (min,max,min,max) reduce + broadcast.
__device__ __forceinline__ void blockRed4(float& a0, float& a1, float& a2, float& a3,
                                          float (*sred)[4], float* bc) {
    for (int off = 32; off; off >>= 1) {
        a0 = fminf(a0, __shfl_down(a0, off, 64));
        a1 = fmaxf(a1, __shfl_down(a1, off, 64));
        a2 = fminf(a2, __shfl_down(a2, off, 64));
        a3 = fmaxf(a3, __shfl_down(a3, off, 64));
    }
    int lane = threadIdx.x & 63, wv = threadIdx.x >> 6;
    if (lane == 0) { sred[wv][0]=a0; sred[wv][1]=a1; sred[wv][2]=a2; sred[wv][3]=a3; }
    __syncthreads();
    if (threadIdx.x == 0) {
#pragma unroll
        for (int w = 1; w < TPB/64; ++w) {
            a0 = fminf(a0, sred[w][0]); a1 = fmaxf(a1, sred[w][1]);
            a2 = fminf(a2, sred[w][2]); a3 = fmaxf(a3, sred[w][3]);
        }
        bc[0]=a0; bc[1]=a1; bc[2]=a2; bc[3]=a3;
    }
    __syncthreads();
    a0=bc[0]; a1=bc[1]; a2=bc[2]; a3=bc[3];
}

__device__ __forceinline__ void blockRed2(float& a0, float& a1,
                                          float (*sred)[4], float* bc) {
    for (int off = 32; off; off >>= 1) {
        a0 = fminf(a0, __shfl_down(a0, off, 64));
        a1 = fmaxf(a1, __shfl_down(a1, off, 64));
    }
    int lane = threadIdx.x & 63, wv = threadIdx.x >> 6;
    if (lane == 0) { sred[wv][0]=a0; sred[wv][1]=a1; }
    __syncthreads();
    if (threadIdx.x == 0) {
#pragma unroll
        for (int w = 1; w < TPB/64; ++w) {
            a0 = fminf(a0, sred[w][0]); a1 = fmaxf(a1, sred[w][1]);
        }
        bc[0]=a0; bc[1]=a1;
    }
    __syncthreads();
    a0=bc[0]; a1=bc[1];
}

__global__ void __launch_bounds__(TPB, 4)
k_fused(const float* __restrict__ flow, const float* __restrict__ depth,
        const int* __restrict__ seg, const float* __restrict__ Km,
        const float* __restrict__ invK, const float* __restrict__ pose,
        float* __restrict__ out, unsigned int* __restrict__ bar,
        float* __restrict__ redA, float* __restrict__ redB,
        unsigned int* __restrict__ partial)
{
    __shared__ unsigned int win[TRW];   // 30720 B
    __shared__ float sred[TPB/64][4];
    __shared__ float bc[4];

    const int wg    = blockIdx.x;
    const int chunk = wg & (SC - 1);
    const int bt    = wg >> 1;
    const int b     = bt / TILES;
    const int tile  = bt - b * TILES;
    const int t0    = tile * TR;

    const float* fx_p = flow + b * 2 * HW;
    const float* fy_p = fx_p + HW;
    const float* iK   = invK + b * 16;
    float P[12];
    computeP(Km + b * 16, pose + b * 16, P);

    for (int i = threadIdx.x; i < TRW; i += TPB) win[i] = 0u;
    __syncthreads();

    // ---- Phase A: winner scan (LDS atomics) + flow min/max (free) ----
    float fmn = INFINITY, fmx = -INFINITY, smn = INFINITY, smx = -INFINITY;
    int s_end = (chunk + 1) * HWC;
    for (int s0 = chunk * HWC + threadIdx.x * 4; s0 < s_end; s0 += TPB * 4) {
        float4 fx4 = *(const float4*)(fx_p + s0);
        float4 fy4 = *(const float4*)(fy_p + s0);
        fmn = fminf(fmn, fminf(fminf(fx4.x, fx4.y), fminf(fx4.z, fx4.w)));
        fmx = fmaxf(fmx, fmaxf(fmaxf(fx4.x, fx4.y), fmaxf(fx4.z, fx4.w)));
        fmn = fminf(fmn, fminf(fminf(fy4.x, fy4.y), fminf(fy4.z, fy4.w)));
        fmx = fmaxf(fmx, fmaxf(fmaxf(fy4.x, fy4.y), fmaxf(fy4.z, fy4.w)));
        int y = s0 / W;
        int x = s0 - y * W;              // groups never cross a row (W%4==0)
        float fxa[4] = {fx4.x, fx4.y, fx4.z, fx4.w};
        float fya[4] = {fy4.x, fy4.y, fy4.z, fy4.w};
#pragma unroll
        for (int j = 0; j < 4; ++j) {
            int cxi = (int)rintf((float)(x + j) + fxa[j]);
            int cyi = (int)rintf((float)y + fya[j]);
            cxi = min(max(cxi, 0), W - 1);
            cyi = min(max(cyi, 0), H - 1);
            if (cyi >= t0 && cyi < t0 + TR) {
                unsigned key = (unsigned)(s0 + j + 1);   // max key == max n
                atomicMax(&win[(cyi - t0) * W + cxi], key);
            }
        }
    }
    __syncthreads();
    {   // partial writeout (coalesced)
        unsigned int* dst = partial + (size_t)wg * TRW;
        for (int i = threadIdx.x; i < TRW; i += TPB) dst[i] = win[i];
    }
    // static-flow min/max: only tile==0 blocks (24 of 384) — exact cover of
    // all (b, chunk) pixels, overlapped with other blocks' scans.
    if (tile == 0) {
        int p_end = b * HW + (chunk + 1) * HWC;
        for (int p0 = b * HW + chunk * HWC + threadIdx.x * 4; p0 < p_end; p0 += TPB * 4) {
            float4 d4 = *(const float4*)(depth + p0);
            int n0 = p0 - b * HW;
            int y  = n0 / W;
            int x0 = n0 - y * W;
            float da[4] = {d4.x, d4.y, d4.z, d4.w};
#pragma unroll
            for (int j = 0; j < 4; ++j) {
                float sx, sy;
                static_flow_P(iK, P, x0 + j, y, da[j], sx, sy);
                smn = fminf(smn, fminf(sx, sy));
                smx = fmaxf(smx, fmaxf(sx, sy));
            }
        }
    }
    blockRed4(fmn, fmx, smn, smx, sred, bc);
    if (threadIdx.x == 0) {
        redA[wg*4+0] = fmn; redA[wg*4+1] = fmx;
        redA[wg*4+2] = smn; redA[wg*4+3] = smx;
    }

    gridBarrier(&bar[0], &bar[1]);

    // ---- Phase B: every block re-reduces redA (6 KB, L2-resident) + check ----
    float gfmn = INFINITY, gfmx = -INFINITY, gsmn = INFINITY, gsmx = -INFINITY;
    for (int i = threadIdx.x; i < NBLK; i += TPB) {
        gfmn = fminf(gfmn, redA[i*4+0]); gfmx = fmaxf(gfmx, redA[i*4+1]);
        gsmn = fminf(gsmn, redA[i*4+2]); gsmx = fmaxf(gsmx, redA[i*4+3]);
    }
    blockRed4(gfmn, gfmx, gsmn, gsmx, sred, bc);

    float cmn = INFINITY, cmx = -INFINITY;
    const int pbase = wg * PPB;    // == b*HW + tile*TRW + chunk*PPB
    for (int g = threadIdx.x; g < PPB / 4; g += TPB) {
        int p0 = pbase + g * 4;
        int n0 = p0 - b * HW;
        int y  = n0 / W;
        int x0 = n0 - y * W;
        float4 fx4 = *(const float4*)(fx_p + n0);
        float4 fy4 = *(const float4*)(fy_p + n0);
        float4 d4  = *(const float4*)(depth + p0);
        float fxa[4] = {fx4.x, fx4.y, fx4.z, fx4.w};
        float fya[4] = {fy4.x, fy4.y, fy4.z, fy4.w};
        float da[4]  = {d4.x, d4.y, d4.z, d4.w};
        float4 cv;
        float* cva = (float*)&cv;
#pragma unroll
        for (int j = 0; j < 4; ++j) {
            float sx, sy;
            static_flow_P(iK, P, x0 + j, y, da[j], sx, sy);
            float dx = norm01(fxa[j], gfmn, gfmx) - norm01(sx, gsmn, gsmx);
            float dy = norm01(fya[j], gfmn, gfmx) - norm01(sy, gsmn, gsmx);
            float c = sqrtf(dx*dx + dy*dy);
            cva[j] = c;
            cmn = fminf(cmn, c); cmx = fmaxf(cmx, c);
        }
        *(float4*)(out + p0) = cv;   // stash check in mask region (overwritten C)
    }
    blockRed2(cmn, cmx, sred, bc);
    if (threadIdx.x == 0) { redB[wg*2] = cmn; redB[wg*2+1] = cmx; }

    gridBarrier(&bar[2], &bar[3]);

    // ---- Phase C: reduce redB + mask + winner merge + exact payload out ----
    float gcmn = INFINITY, gcmx = -INFINITY;
    for (int i = threadIdx.x; i < NBLK; i += TPB) {
        gcmn = fminf(gcmn, redB[2*i]); gcmx = fmaxf(gcmx, redB[2*i+1]);
    }
    blockRed2(gcmn, gcmx, sred, bc);

    const unsigned int* pb0 = partial + (size_t)(bt * SC) * TRW + chunk * PPB;
    const int nbase = t0 * W + chunk * PPB;   // in-batch target index base
    for (int i = threadIdx.x; i < PPB; i += TPB) {
        int p = pbase + i;
        float c  = out[p];                    // stashed check
        float cn = (c - gcmn) / (gcmx - gcmn);
        out[p] = (cn < 0.98f) ? 1.0f : 0.0f;

        unsigned k = max(pb0[i], pb0[i + TRW]);   // merge both source chunks
        float bx = 0.0f, by = 0.0f, sg = 0.0f;
        if (k) {
            int nw = (int)k - 1;                  // winning source index
            bx = -fx_p[nw];                       // exact payload via gather
            by = -fy_p[nw];
            sg = seg[b*HW + nw] ? 1.0f : 0.0f;
        }
        int n = nbase + i;
        out[BHW + b*2*HW + n]      = bx;
        out[BHW + b*2*HW + HW + n] = by;
        out[3*BHW + b*HW + n]      = sg;
    }
}

} // namespace

extern "C" void kernel_launch(void* const* d_in, const int* in_sizes, int n_in,
                              void* d_out, int out_size, void* d_ws, size_t ws_size,
                              hipStream_t stream) {
    const float* flow  = (const float*)d_in[0];
    const float* depth = (const float*)d_in[1];
    const float* Km    = (const float*)d_in[2];
    const float* invK  = (const float*)d_in[3];
    const float* pose  = (const float*)d_in[4];
    const int*   seg   = (const int*)d_in[5];
    float* out = (float*)d_out;

    unsigned int* bar = (unsigned int*)d_ws;
    float* redA = (float*)((char*)d_ws + 4096);
    float* redB = (float*)((char*)d_ws + 12288);
    unsigned int* partial = (unsigned int*)((char*)d_ws + 16384);  // 11.8 MB

    hipMemsetAsync(bar, 0, 32, stream);   // ws is re-poisoned every call
    k_fused<<<NBLK, TPB, 0, stream>>>(flow, depth, seg, Km, invK, pose,
                                      out, bar, redA, redB, partial);
}

// Round 8
// 148.744 us; speedup vs baseline: 2.3109x; 2.3109x over previous
//
#include <hip/hip_runtime.h>
#include <math.h>

// Match numpy (no FMA contraction) — mask boundary is bit-sensitive.
#pragma clang fp contract(off)

namespace {

constexpr int B = 12, H = 192, W = 640;
constexpr int HW  = H * W;        // 122880
constexpr int BHW = B * HW;       // 1474560
constexpr float EPS = 1e-7f;

constexpr int TR    = 12;         // target-tile rows per winner block
constexpr int TILES = H / TR;     // 16 tiles/batch
constexpr int TRW   = TR * W;     // 7680 targets per tile
constexpr int SC    = 2;          // source chunks per tile
constexpr int HWC   = HW / SC;    // 61440 sources per chunk
constexpr int NBLK  = B * TILES * SC;  // 384 winner blocks
constexpr int SPB   = HWC / TILES;     // 3840 static-pass pixels per winner block
constexpr int WTPB  = 1024;
constexpr int RBLK  = 256;             // red2 / mask grid
constexpr int RTPB  = 1024;

// ws: redA[NBLK*4] f32 @ +0 | redB[RBLK*2] f32 @ +8192 |
//     partial[NBLK*TRW] u32 @ +16384  (11.8 MB — R4/R5-proven footprint)
// check[] scratch lives in out[0..BHW) between k_red2 and k_mask (R7-proven).

// P = (K @ pose)[:3,:] — arithmetic identical to reference einsum
// (left-assoc, contract off); hoisting changes no per-element value.
__device__ __forceinline__ void computeP(const float* __restrict__ Kb,
                                         const float* __restrict__ Po, float* P) {
#pragma unroll
    for (int i = 0; i < 3; ++i)
#pragma unroll
        for (int j = 0; j < 4; ++j) {
            float s = Kb[i*4+0] * Po[0*4+j];
            s = s + Kb[i*4+1] * Po[1*4+j];
            s = s + Kb[i*4+2] * Po[2*4+j];
            s = s + Kb[i*4+3] * Po[3*4+j];
            P[i*4+j] = s;
        }
}

__device__ __forceinline__ void static_flow_P(
    const float* __restrict__ iK, const float* __restrict__ P,
    int x, int y, float d, float& sx, float& sy)
{
    float fx = (float)x, fy = (float)y;
    float cam0 = iK[0]*fx + iK[1]*fy + iK[2];
    float cam1 = iK[4]*fx + iK[5]*fy + iK[6];
    float cam2 = iK[8]*fx + iK[9]*fy + iK[10];
    cam0 = d * cam0; cam1 = d * cam1; cam2 = d * cam2;
    float cp0 = P[0]*cam0 + P[1]*cam1 + P[2]*cam2  + P[3];
    float cp1 = P[4]*cam0 + P[5]*cam1 + P[6]*cam2  + P[7];
    float cp2 = P[8]*cam0 + P[9]*cam1 + P[10]*cam2 + P[11];
    float pz = cp2 + EPS;
    sx = cp0 / pz - fx;
    sy = cp1 / pz - fy;
}

__device__ __forceinline__ float norm01(float v, float mn, float mx) {
    return (2.0f * (v - mn)) / (mx - mn) - 1.0f;
}

// Block-wide reduce for 1024-thread blocks (16 waves) + broadcast.
__device__ __forceinline__ void blockRed4(float& a0, float& a1, float& a2, float& a3,
                                          float (*sred)[4], float* bc) {
    for (int off = 32; off; off >>= 1) {
        a0 = fminf(a0, __shfl_down(a0, off, 64));
        a1 = fmaxf(a1, __shfl_down(a1, off, 64));
        a2 = fminf(a2, __shfl_down(a2, off, 64));
        a3 = fmaxf(a3, __shfl_down(a3, off, 64));
    }
    int lane = threadIdx.x & 63, wv = threadIdx.x >> 6;
    if (lane == 0) { sred[wv][0]=a0; sred[wv][1]=a1; sred[wv][2]=a2; sred[wv][3]=a3; }
    __syncthreads();
    if (threadIdx.x == 0) {
#pragma unroll
        for (int w = 1; w < 16; ++w) {
            a0 = fminf(a0, sred[w][0]); a1 = fmaxf(a1, sred[w][1]);
            a2 = fminf(a2, sred[w][2]); a3 = fmaxf(a3, sred[w][3]);
        }
        bc[0]=a0; bc[1]=a1; bc[2]=a2; bc[3]=a3;
    }
    __syncthreads();
    a0=bc[0]; a1=bc[1]; a2=bc[2]; a3=bc[3];
}

__device__ __forceinline__ void blockRed2(float& a0, float& a1,
                                          float (*sred)[4], float* bc) {
    for (int off = 32; off; off >>= 1) {
        a0 = fminf(a0, __shfl_down(a0, off, 64));
        a1 = fmaxf(a1, __shfl_down(a1, off, 64));
    }
    int lane = threadIdx.x & 63, wv = threadIdx.x >> 6;
    if (lane == 0) { sred[wv][0]=a0; sred[wv][1]=a1; }
    __syncthreads();
    if (threadIdx.x == 0) {
#pragma unroll
        for (int w = 1; w < 16; ++w) {
            a0 = fminf(a0, sred[w][0]); a1 = fmaxf(a1, sred[w][1]);
        }
        bc[0]=a0; bc[1]=a1;
    }
    __syncthreads();
    a0=bc[0]; a1=bc[1];
}

// Dispatch 1: winner scan (LDS atomics, no global atomics) + flow min/max on
// the same loads + this block's 3840-pixel slice of static-flow min/max.
// Partials -> redA; winner partials -> ws (coalesced).
__global__ void __launch_bounds__(WTPB)
k_winner(const float* __restrict__ flow, const float* __restrict__ depth,
         const float* __restrict__ Km, const float* __restrict__ invK,
         const float* __restrict__ pose,
         unsigned int* __restrict__ partial, float* __restrict__ redA) {
    __shared__ unsigned int win[TRW];   // 30720 B
    __shared__ float sred[16][4];
    __shared__ float bc[4];

    const int wg    = blockIdx.x;
    const int chunk = wg & (SC - 1);
    const int bt    = wg >> 1;
    const int b     = bt / TILES;
    const int tile  = bt - b * TILES;
    const int t0    = tile * TR;

    const float* fx_p = flow + b * 2 * HW;
    const float* fy_p = fx_p + HW;

    for (int i = threadIdx.x; i < TRW; i += WTPB) win[i] = 0u;
    __syncthreads();

    float fmn = INFINITY, fmx = -INFINITY, smn = INFINITY, smx = -INFINITY;
    // winner scan over this chunk's sources; flow min/max rides along free.
    int s_end = (chunk + 1) * HWC;
    for (int s0 = chunk * HWC + threadIdx.x * 4; s0 < s_end; s0 += WTPB * 4) {
        float4 fx4 = *(const float4*)(fx_p + s0);
        float4 fy4 = *(const float4*)(fy_p + s0);
        fmn = fminf(fmn, fminf(fminf(fx4.x, fx4.y), fminf(fx4.z, fx4.w)));
        fmx = fmaxf(fmx, fmaxf(fmaxf(fx4.x, fx4.y), fmaxf(fx4.z, fx4.w)));
        fmn = fminf(fmn, fminf(fminf(fy4.x, fy4.y), fminf(fy4.z, fy4.w)));
        fmx = fmaxf(fmx, fmaxf(fmaxf(fy4.x, fy4.y), fmaxf(fy4.z, fy4.w)));
        int y = s0 / W;
        int x = s0 - y * W;              // groups never cross a row (W%4==0)
        float fxa[4] = {fx4.x, fx4.y, fx4.z, fx4.w};
        float fya[4] = {fy4.x, fy4.y, fy4.z, fy4.w};
#pragma unroll
        for (int j = 0; j < 4; ++j) {
            int cxi = (int)rintf((float)(x + j) + fxa[j]);
            int cyi = (int)rintf((float)y + fya[j]);
            cxi = min(max(cxi, 0), W - 1);
            cyi = min(max(cyi, 0), H - 1);
            if (cyi >= t0 && cyi < t0 + TR) {
                unsigned key = (unsigned)(s0 + j + 1);   // max key == max n
                atomicMax(&win[(cyi - t0) * W + cxi], key);
            }
        }
    }
    __syncthreads();
    {   // partial writeout (coalesced)
        unsigned int* dst = partial + (size_t)wg * TRW;
        for (int i = threadIdx.x; i < TRW; i += WTPB) dst[i] = win[i];
    }

    // static-flow min/max over THIS block's distinct 3840-pixel slice
    // (384 blocks exactly tile BHW; rows stay aligned: SPB % W == 0).
    {
        const float* iK = invK + b * 16;
        float P[12];
        computeP(Km + b * 16, pose + b * 16, P);
        int n0s = chunk * HWC + tile * SPB;
        if (threadIdx.x < SPB / 4) {
            int n = n0s + threadIdx.x * 4;
            int y = n / W;
            int x0 = n - y * W;
            float4 d4 = *(const float4*)(depth + b * HW + n);
            float da[4] = {d4.x, d4.y, d4.z, d4.w};
#pragma unroll
            for (int j = 0; j < 4; ++j) {
                float sx, sy;
                static_flow_P(iK, P, x0 + j, y, da[j], sx, sy);
                smn = fminf(smn, fminf(sx, sy));
                smx = fmaxf(smx, fmaxf(sx, sy));
            }
        }
    }
    blockRed4(fmn, fmx, smn, smx, sred, bc);
    if (threadIdx.x == 0) {
        redA[wg*4+0] = fmn; redA[wg*4+1] = fmx;
        redA[wg*4+2] = smn; redA[wg*4+3] = smx;
    }
}

// Dispatch 2: re-reduce redA (1.5 KB, L2-hit) + check pass; stash check into
// out[0..BHW) (mask region is scratch until k_mask); partials -> redB.
__global__ void __launch_bounds__(RTPB)
k_red2(const float* __restrict__ flow, const float* __restrict__ depth,
       const float* __restrict__ Km, const float* __restrict__ invK,
       const float* __restrict__ pose,
       const float* __restrict__ redA, float* __restrict__ redB,
       float* __restrict__ out) {
    __shared__ float sred[16][4];
    __shared__ float bc[4];

    float gfmn = INFINITY, gfmx = -INFINITY, gsmn = INFINITY, gsmx = -INFINITY;
    for (int i = threadIdx.x; i < NBLK; i += RTPB) {
        gfmn = fminf(gfmn, redA[i*4+0]); gfmx = fmaxf(gfmx, redA[i*4+1]);
        gsmn = fminf(gsmn, redA[i*4+2]); gsmx = fmaxf(gsmx, redA[i*4+3]);
    }
    blockRed4(gfmn, gfmx, gsmn, gsmx, sred, bc);

    float cmn = INFINITY, cmx = -INFINITY;
    int bCur = -1;
    float P[12];
    int stride = gridDim.x * blockDim.x;
    for (int g = blockIdx.x * blockDim.x + threadIdx.x; g < BHW / 4; g += stride) {
        int p0 = g * 4;
        int b  = p0 / HW;
        if (b != bCur) { computeP(Km + b * 16, pose + b * 16, P); bCur = b; }
        const float* iK = invK + b * 16;
        int n0 = p0 - b * HW;
        int y  = n0 / W;
        int x0 = n0 - y * W;
        float4 fx4 = *(const float4*)(flow + b*2*HW + n0);
        float4 fy4 = *(const float4*)(flow + b*2*HW + HW + n0);
        float4 d4  = *(const float4*)(depth + p0);
        float fxa[4] = {fx4.x, fx4.y, fx4.z, fx4.w};
        float fya[4] = {fy4.x, fy4.y, fy4.z, fy4.w};
        float da[4]  = {d4.x, d4.y, d4.z, d4.w};
        float4 cv;
        float* cva = (float*)&cv;
#pragma unroll
        for (int j = 0; j < 4; ++j) {
            float sx, sy;
            static_flow_P(iK, P, x0 + j, y, da[j], sx, sy);
            float dx = norm01(fxa[j], gfmn, gfmx) - norm01(sx, gsmn, gsmx);
            float dy = norm01(fya[j], gfmn, gfmx) - norm01(sy, gsmn, gsmx);
            float c = sqrtf(dx*dx + dy*dy);
            cva[j] = c;
            cmn = fminf(cmn, c); cmx = fmaxf(cmx, c);
        }
        *(float4*)(out + p0) = cv;   // stash check (overwritten by k_mask)
    }
    blockRed2(cmn, cmx, sred, bc);
    if (threadIdx.x == 0) { redB[blockIdx.x*2] = cmn; redB[blockIdx.x*2+1] = cmx; }
}

// Dispatch 3: re-reduce redB + threshold stashed check in-place + winner
// merge + exact-payload gathers. No static_flow, no flow/depth streams.
__global__ void __launch_bounds__(RTPB)
k_mask(const float* __restrict__ flow, const int* __restrict__ seg,
       const float* __restrict__ redB, const unsigned int* __restrict__ partial,
       float* __restrict__ out) {
    __shared__ float sred[16][4];
    __shared__ float bc[4];

    float gcmn = INFINITY, gcmx = -INFINITY;
    for (int i = threadIdx.x; i < RBLK; i += RTPB) {
        gcmn = fminf(gcmn, redB[2*i]); gcmx = fmaxf(gcmx, redB[2*i+1]);
    }
    blockRed2(gcmn, gcmx, sred, bc);

    int stride = gridDim.x * blockDim.x;
    for (int p = blockIdx.x * blockDim.x + threadIdx.x; p < BHW; p += stride) {
        float c  = out[p];                    // stashed check
        float cn = (c - gcmn) / (gcmx - gcmn);
        out[p] = (cn < 0.98f) ? 1.0f : 0.0f;

        int b    = p / HW;
        int n    = p - b * HW;
        int tile = n / TRW;
        int off  = n - tile * TRW;
        int bt   = b * TILES + tile;
        unsigned k = max(partial[(size_t)(bt*2)   * TRW + off],
                         partial[(size_t)(bt*2+1) * TRW + off]);
        float bx = 0.0f, by = 0.0f, sg = 0.0f;
        if (k) {
            int nw = (int)k - 1;                  // winning source index
            bx = -flow[b*2*HW + nw];              // exact payload via gather
            by = -flow[b*2*HW + HW + nw];
            sg = seg[b*HW + nw] ? 1.0f : 0.0f;
        }
        out[BHW + b*2*HW + n]      = bx;
        out[BHW + b*2*HW + HW + n] = by;
        out[3*BHW + p]             = sg;
    }
}

} // namespace

extern "C" void kernel_launch(void* const* d_in, const int* in_sizes, int n_in,
                              void* d_out, int out_size, void* d_ws, size_t ws_size,
                              hipStream_t stream) {
    const float* flow  = (const float*)d_in[0];
    const float* depth = (const float*)d_in[1];
    const float* Km    = (const float*)d_in[2];
    const float* invK  = (const float*)d_in[3];
    const float* pose  = (const float*)d_in[4];
    const int*   seg   = (const int*)d_in[5];
    float* out = (float*)d_out;

    float* redA = (float*)d_ws;
    float* redB = (float*)((char*)d_ws + 8192);
    unsigned int* partial = (unsigned int*)((char*)d_ws + 16384);  // 11.8 MB

    k_winner<<<NBLK, WTPB, 0, stream>>>(flow, depth, Km, invK, pose, partial, redA);
    k_red2  <<<RBLK, RTPB, 0, stream>>>(flow, depth, Km, invK, pose, redA, redB, out);
    k_mask  <<<RBLK, RTPB, 0, stream>>>(flow, seg, redB, partial, out);
}

// Round 10
// 138.712 us; speedup vs baseline: 2.4780x; 1.0723x over previous
//
#include <hip/hip_runtime.h>
#include <math.h>

// Match numpy (no FMA contraction) — mask boundary is bit-sensitive.
#pragma clang fp contract(off)

namespace {

constexpr int B = 12, H = 192, W = 640;
constexpr int HW  = H * W;        // 122880
constexpr int BHW = B * HW;       // 1474560
constexpr float EPS = 1e-7f;

constexpr int TR    = 24;         // target-tile rows per winner block
constexpr int TILES = H / TR;     // 8 tiles/batch  (scan traffic ∝ TILES)
constexpr int TRW   = TR * W;     // 15360 targets per tile
constexpr int SC    = 4;          // source chunks per tile (merge ∝ SC, u16)
constexpr int HWC   = HW / SC;    // 30720 sources per chunk (local key ≤ 30720 < 2^16)
constexpr int NBLK  = B * TILES * SC;  // 384 winner blocks
constexpr int SPB   = HW / (TILES * SC); // 3840 static-pass pixels per block
constexpr int WTPB  = 1024;
constexpr int RBLK  = 256;             // red2 / mask grid
constexpr int RTPB  = 1024;

// ws: redA[NBLK*4] f32 @ +0 | redB[RBLK*2] f32 @ +8192 |
//     partial[NBLK*TRW] u16 @ +16384  (11.8 MB — same proven footprint)
// check[] scratch lives in out[0..BHW) between k_red2 and k_mask (R7-proven).
// Winner keys are chunk-LOCAL indices: global n = chunk*HWC + local - 1, and
// any nonzero key in a higher chunk beats all keys in lower chunks, so the
// cross-chunk merge is "highest chunk with nonzero key" — exact LWW.

// P = (K @ pose)[:3,:] — arithmetic identical to reference einsum
// (left-assoc, contract off); hoisting changes no per-element value.
__device__ __forceinline__ void computeP(const float* __restrict__ Kb,
                                         const float* __restrict__ Po, float* P) {
#pragma unroll
    for (int i = 0; i < 3; ++i)
#pragma unroll
        for (int j = 0; j < 4; ++j) {
            float s = Kb[i*4+0] * Po[0*4+j];
            s = s + Kb[i*4+1] * Po[1*4+j];
            s = s + Kb[i*4+2] * Po[2*4+j];
            s = s + Kb[i*4+3] * Po[3*4+j];
            P[i*4+j] = s;
        }
}

__device__ __forceinline__ void static_flow_P(
    const float* __restrict__ iK, const float* __restrict__ P,
    int x, int y, float d, float& sx, float& sy)
{
    float fx = (float)x, fy = (float)y;
    float cam0 = iK[0]*fx + iK[1]*fy + iK[2];
    float cam1 = iK[4]*fx + iK[5]*fy + iK[6];
    float cam2 = iK[8]*fx + iK[9]*fy + iK[10];
    cam0 = d * cam0; cam1 = d * cam1; cam2 = d * cam2;
    float cp0 = P[0]*cam0 + P[1]*cam1 + P[2]*cam2  + P[3];
    float cp1 = P[4]*cam0 + P[5]*cam1 + P[6]*cam2  + P[7];
    float cp2 = P[8]*cam0 + P[9]*cam1 + P[10]*cam2 + P[11];
    float pz = cp2 + EPS;
    sx = cp0 / pz - fx;
    sy = cp1 / pz - fy;
}

__device__ __forceinline__ float norm01(float v, float mn, float mx) {
    return (2.0f * (v - mn)) / (mx - mn) - 1.0f;
}

// Block-wide reduce for 1024-thread blocks (16 waves) + broadcast.
__device__ __forceinline__ void blockRed4(float& a0, float& a1, float& a2, float& a3,
                                          float (*sred)[4], float* bc) {
    for (int off = 32; off; off >>= 1) {
        a0 = fminf(a0, __shfl_down(a0, off, 64));
        a1 = fmaxf(a1, __shfl_down(a1, off, 64));
        a2 = fminf(a2, __shfl_down(a2, off, 64));
        a3 = fmaxf(a3, __shfl_down(a3, off, 64));
    }
    int lane = threadIdx.x & 63, wv = threadIdx.x >> 6;
    if (lane == 0) { sred[wv][0]=a0; sred[wv][1]=a1; sred[wv][2]=a2; sred[wv][3]=a3; }
    __syncthreads();
    if (threadIdx.x == 0) {
#pragma unroll
        for (int w = 1; w < 16; ++w) {
            a0 = fminf(a0, sred[w][0]); a1 = fmaxf(a1, sred[w][1]);
            a2 = fminf(a2, sred[w][2]); a3 = fmaxf(a3, sred[w][3]);
        }
        bc[0]=a0; bc[1]=a1; bc[2]=a2; bc[3]=a3;
    }
    __syncthreads();
    a0=bc[0]; a1=bc[1]; a2=bc[2]; a3=bc[3];
}

__device__ __forceinline__ void blockRed2(float& a0, float& a1,
                                          float (*sred)[4], float* bc) {
    for (int off = 32; off; off >>= 1) {
        a0 = fminf(a0, __shfl_down(a0, off, 64));
        a1 = fmaxf(a1, __shfl_down(a1, off, 64));
    }
    int lane = threadIdx.x & 63, wv = threadIdx.x >> 6;
    if (lane == 0) { sred[wv][0]=a0; sred[wv][1]=a1; }
    __syncthreads();
    if (threadIdx.x == 0) {
#pragma unroll
        for (int w = 1; w < 16; ++w) {
            a0 = fminf(a0, sred[w][0]); a1 = fmaxf(a1, sred[w][1]);
        }
        bc[0]=a0; bc[1]=a1;
    }
    __syncthreads();
    a0=bc[0]; a1=bc[1];
}

// Dispatch 1: winner scan (LDS atomics, chunk-local keys) + flow min/max on
// the same loads + this block's 3840-pixel slice of static-flow min/max.
__global__ void __launch_bounds__(WTPB, 8)
k_winner(const float* __restrict__ flow, const float* __restrict__ depth,
         const float* __restrict__ Km, const float* __restrict__ invK,
         const float* __restrict__ pose,
         unsigned short* __restrict__ partial, float* __restrict__ redA) {
    __shared__ unsigned int win[TRW];   // 61440 B -> 2 blocks/CU
    __shared__ float sred[16][4];
    __shared__ float bc[4];

    const int wg    = blockIdx.x;
    const int chunk = wg & (SC - 1);
    const int bt    = wg >> 2;
    const int b     = bt / TILES;
    const int tile  = bt - b * TILES;
    const int t0    = tile * TR;

    const float* fx_p = flow + b * 2 * HW;
    const float* fy_p = fx_p + HW;

    for (int i = threadIdx.x; i < TRW; i += WTPB) win[i] = 0u;
    __syncthreads();

    float fmn = INFINITY, fmx = -INFINITY, smn = INFINITY, smx = -INFINITY;
    // winner scan over this chunk's sources; flow min/max rides along free.
    const int s_beg = chunk * HWC;
    const int s_end = s_beg + HWC;
    for (int s0 = s_beg + threadIdx.x * 4; s0 < s_end; s0 += WTPB * 4) {
        float4 fx4 = *(const float4*)(fx_p + s0);
        float4 fy4 = *(const float4*)(fy_p + s0);
        fmn = fminf(fmn, fminf(fminf(fx4.x, fx4.y), fminf(fx4.z, fx4.w)));
        fmx = fmaxf(fmx, fmaxf(fmaxf(fx4.x, fx4.y), fmaxf(fx4.z, fx4.w)));
        fmn = fminf(fmn, fminf(fminf(fy4.x, fy4.y), fminf(fy4.z, fy4.w)));
        fmx = fmaxf(fmx, fmaxf(fmaxf(fy4.x, fy4.y), fmaxf(fy4.z, fy4.w)));
        int y = s0 / W;
        int x = s0 - y * W;              // groups never cross a row (W%4==0)
        float fxa[4] = {fx4.x, fx4.y, fx4.z, fx4.w};
        float fya[4] = {fy4.x, fy4.y, fy4.z, fy4.w};
#pragma unroll
        for (int j = 0; j < 4; ++j) {
            int cxi = (int)rintf((float)(x + j) + fxa[j]);
            int cyi = (int)rintf((float)y + fya[j]);
            cxi = min(max(cxi, 0), W - 1);
            cyi = min(max(cyi, 0), H - 1);
            if (cyi >= t0 && cyi < t0 + TR) {
                unsigned key = (unsigned)(s0 + j + 1 - s_beg);  // local, ≤30720
                atomicMax(&win[(cyi - t0) * W + cxi], key);
            }
        }
    }
    __syncthreads();
    {   // partial writeout (coalesced u16)
        unsigned short* dst = partial + (size_t)wg * TRW;
        for (int i = threadIdx.x; i < TRW; i += WTPB)
            dst[i] = (unsigned short)win[i];
    }

    // static-flow min/max over THIS block's distinct 3840-pixel slice
    // (384 blocks exactly tile BHW; rows aligned: SPB % W == 0).
    {
        const float* iK = invK + b * 16;
        float P[12];
        computeP(Km + b * 16, pose + b * 16, P);
        int n0s = chunk * HWC + tile * SPB;
        if (threadIdx.x < SPB / 4) {
            int n = n0s + threadIdx.x * 4;
            int y = n / W;
            int x0 = n - y * W;
            float4 d4 = *(const float4*)(depth + b * HW + n);
            float da[4] = {d4.x, d4.y, d4.z, d4.w};
#pragma unroll
            for (int j = 0; j < 4; ++j) {
                float sx, sy;
                static_flow_P(iK, P, x0 + j, y, da[j], sx, sy);
                smn = fminf(smn, fminf(sx, sy));
                smx = fmaxf(smx, fmaxf(sx, sy));
            }
        }
    }
    blockRed4(fmn, fmx, smn, smx, sred, bc);
    if (threadIdx.x == 0) {
        redA[wg*4+0] = fmn; redA[wg*4+1] = fmx;
        redA[wg*4+2] = smn; redA[wg*4+3] = smx;
    }
}

// Dispatch 2: re-reduce redA (L2-hit) + check pass; stash check into
// out[0..BHW); partials -> redB.
__global__ void __launch_bounds__(RTPB)
k_red2(const float* __restrict__ flow, const float* __restrict__ depth,
       const float* __restrict__ Km, const float* __restrict__ invK,
       const float* __restrict__ pose,
       const float* __restrict__ redA, float* __restrict__ redB,
       float* __restrict__ out) {
    __shared__ float sred[16][4];
    __shared__ float bc[4];

    float gfmn = INFINITY, gfmx = -INFINITY, gsmn = INFINITY, gsmx = -INFINITY;
    for (int i = threadIdx.x; i < NBLK; i += RTPB) {
        gfmn = fminf(gfmn, redA[i*4+0]); gfmx = fmaxf(gfmx, redA[i*4+1]);
        gsmn = fminf(gsmn, redA[i*4+2]); gsmx = fmaxf(gsmx, redA[i*4+3]);
    }
    blockRed4(gfmn, gfmx, gsmn, gsmx, sred, bc);

    float cmn = INFINITY, cmx = -INFINITY;
    int bCur = -1;
    float P[12];
    int stride = gridDim.x * blockDim.x;
    for (int g = blockIdx.x * blockDim.x + threadIdx.x; g < BHW / 4; g += stride) {
        int p0 = g * 4;
        int b  = p0 / HW;
        if (b != bCur) { computeP(Km + b * 16, pose + b * 16, P); bCur = b; }
        const float* iK = invK + b * 16;
        int n0 = p0 - b * HW;
        int y  = n0 / W;
        int x0 = n0 - y * W;
        float4 fx4 = *(const float4*)(flow + b*2*HW + n0);
        float4 fy4 = *(const float4*)(flow + b*2*HW + HW + n0);
        float4 d4  = *(const float4*)(depth + p0);
        float fxa[4] = {fx4.x, fx4.y, fx4.z, fx4.w};
        float fya[4] = {fy4.x, fy4.y, fy4.z, fy4.w};
        float da[4]  = {d4.x, d4.y, d4.z, d4.w};
        float4 cv;
        float* cva = (float*)&cv;
#pragma unroll
        for (int j = 0; j < 4; ++j) {
            float sx, sy;
            static_flow_P(iK, P, x0 + j, y, da[j], sx, sy);
            float dx = norm01(fxa[j], gfmn, gfmx) - norm01(sx, gsmn, gsmx);
            float dy = norm01(fya[j], gfmn, gfmx) - norm01(sy, gsmn, gsmx);
            float c = sqrtf(dx*dx + dy*dy);
            cva[j] = c;
            cmn = fminf(cmn, c); cmx = fmaxf(cmx, c);
        }
        *(float4*)(out + p0) = cv;   // stash check (overwritten by k_mask)
    }
    blockRed2(cmn, cmx, sred, bc);
    if (threadIdx.x == 0) { redB[blockIdx.x*2] = cmn; redB[blockIdx.x*2+1] = cmx; }
}

// Dispatch 3: re-reduce redB + threshold stashed check in-place + winner
// merge (highest nonzero chunk) + exact-payload gathers.
__global__ void __launch_bounds__(RTPB)
k_mask(const float* __restrict__ flow, const int* __restrict__ seg,
       const float* __restrict__ redB, const unsigned short* __restrict__ partial,
       float* __restrict__ out) {
    __shared__ float sred[16][4];
    __shared__ float bc[4];

    float gcmn = INFINITY, gcmx = -INFINITY;
    for (int i = threadIdx.x; i < RBLK; i += RTPB) {
        gcmn = fminf(gcmn, redB[2*i]); gcmx = fmaxf(gcmx, redB[2*i+1]);
    }
    blockRed2(gcmn, gcmx, sred, bc);

    int stride = gridDim.x * blockDim.x;
    for (int p = blockIdx.x * blockDim.x + threadIdx.x; p < BHW; p += stride) {
        float c  = out[p];                    // stashed check
        float cn = (c - gcmn) / (gcmx - gcmn);
        out[p] = (cn < 0.98f) ? 1.0f : 0.0f;

        int b    = p / HW;
        int n    = p - b * HW;
        int tile = n / TRW;
        int off  = n - tile * TRW;
        const unsigned short* base =
            partial + (size_t)(b * TILES + tile) * SC * TRW + off;
        // highest chunk with nonzero key wins (global n = chunk*HWC + key - 1)
        int nw = -1;
#pragma unroll
        for (int cch = 0; cch < SC; ++cch) {
            unsigned k = base[(size_t)cch * TRW];
            if (k) nw = cch * HWC + (int)k - 1;
        }
        float bx = 0.0f, by = 0.0f, sg = 0.0f;
        if (nw >= 0) {
            bx = -flow[b*2*HW + nw];              // exact payload via gather
            by = -flow[b*2*HW + HW + nw];
            sg = seg[b*HW + nw] ? 1.0f : 0.0f;
        }
        out[BHW + b*2*HW + n]      = bx;
        out[BHW + b*2*HW + HW + n] = by;
        out[3*BHW + p]             = sg;
    }
}

} // namespace

extern "C" void kernel_launch(void* const* d_in, const int* in_sizes, int n_in,
                              void* d_out, int out_size, void* d_ws, size_t ws_size,
                              hipStream_t stream) {
    const float* flow  = (const float*)d_in[0];
    const float* depth = (const float*)d_in[1];
    const float* Km    = (const float*)d_in[2];
    const float* invK  = (const float*)d_in[3];
    const float* pose  = (const float*)d_in[4];
    const int*   seg   = (const int*)d_in[5];
    float* out = (float*)d_out;

    float* redA = (float*)d_ws;
    float* redB = (float*)((char*)d_ws + 8192);
    unsigned short* partial = (unsigned short*)((char*)d_ws + 16384);  // 11.8 MB

    k_winner<<<NBLK, WTPB, 0, stream>>>(flow, depth, Km, invK, pose, partial, redA);
    k_red2  <<<RBLK, RTPB, 0, stream>>>(flow, depth, Km, invK, pose, redA, redB, out);
    k_mask  <<<RBLK, RTPB, 0, stream>>>(flow, seg, redB, partial, out);
}